// Round 1
// baseline (368.299 us; speedup 1.0000x reference)
//
#include <hip/hip_runtime.h>
#include <math.h>

#define N_NODES 10000
#define N_EDGES 160000
#define NEL 10
#define C 64
#define NB 8
#define SHD 9
#define MLPH 16
#define CSH 576
#define R_MAX 5.0f
#define INV_AVG 0.03125f

__device__ __forceinline__ float silu_f(float v) {
    return v / (1.0f + __expf(-v));
}

// ---------------------------------------------------------------------------
// K1: per-edge geometry + radial MLP input, compact active edges
// ---------------------------------------------------------------------------
__global__ __launch_bounds__(256) void k_edge(
    const float* __restrict__ pos, const float* __restrict__ shifts,
    const int* __restrict__ ei, const float* __restrict__ Wr1,
    int* __restrict__ cnt, int* __restrict__ act_snd, int* __restrict__ act_rcv,
    float* __restrict__ act_sh, float* __restrict__ act_h0, float* __restrict__ act_h1)
{
    int e = blockIdx.x * 256 + threadIdx.x;
    int snd = ei[e];
    int rcv = ei[N_EDGES + e];
    float vx = pos[rcv * 3 + 0] - pos[snd * 3 + 0] + shifts[e * 3 + 0];
    float vy = pos[rcv * 3 + 1] - pos[snd * 3 + 1] + shifts[e * 3 + 1];
    float vz = pos[rcv * 3 + 2] - pos[snd * 3 + 2] + shifts[e * 3 + 2];
    float r = sqrtf(vx * vx + vy * vy + vz * vz) + 1e-9f;
    float x = r / R_MAX;
    bool active = x < 1.0f;

    unsigned long long m = __ballot(active);
    int lane = threadIdx.x & 63;
    int base = 0;
    if (m) {
        int leader = __ffsll((unsigned long long)m) - 1;
        if (lane == leader) base = atomicAdd(cnt, __popcll(m));
        base = __shfl(base, leader);
    }
    if (!active) return;

    int p = base + __popcll(m & ((1ull << lane) - 1ull));
    act_snd[p] = snd;
    act_rcv[p] = rcv;

    // spherical harmonics (l<=2, hard-coded normalization from reference)
    float inv_r = 1.0f / r;
    float ux = vx * inv_r, uy = vy * inv_r, uz = vz * inv_r;
    const float s3 = 1.7320508075688772f;
    const float s5 = 2.23606797749979f;
    const float s15 = 3.872983346207417f;
    act_sh[p * 9 + 0] = 1.0f;
    act_sh[p * 9 + 1] = s3 * ux;
    act_sh[p * 9 + 2] = s3 * uy;
    act_sh[p * 9 + 3] = s3 * uz;
    act_sh[p * 9 + 4] = s15 * ux * uy;
    act_sh[p * 9 + 5] = s15 * uy * uz;
    act_sh[p * 9 + 6] = 0.5f * s5 * (3.0f * uz * uz - 1.0f);
    act_sh[p * 9 + 7] = s15 * ux * uz;
    act_sh[p * 9 + 8] = 0.5f * s15 * (ux * ux - uy * uy);

    // radial: bessel * polynomial cutoff (p=6)
    float x2 = x * x;
    float x3 = x2 * x;
    float x6 = x3 * x3;
    float x7 = x6 * x;
    float x8 = x7 * x;
    float fc = 1.0f - 28.0f * x6 + 48.0f * x7 - 21.0f * x8;
    float theta = 3.14159265358979323846f * r / R_MAX;
    float s1 = sinf(theta), c1 = cosf(theta);
    float ef[NB];
    float sn = s1, cn = c1;
    float scale = 0.6324555320336759f * inv_r * fc;   // sqrt(2/R_MAX)/r*fc
    ef[0] = scale * sn;
    #pragma unroll
    for (int n = 1; n < NB; n++) {
        float sn1 = sn * c1 + cn * s1;
        float cn1 = cn * c1 - sn * s1;
        sn = sn1; cn = cn1;
        ef[n] = scale * sn;
    }

    // hidden = silu(ef @ W_r1[t]) for both layers
    #pragma unroll
    for (int t = 0; t < 2; t++) {
        float* dst = (t == 0) ? act_h0 : act_h1;
        const float* W = Wr1 + t * NB * MLPH;
        #pragma unroll
        for (int mm = 0; mm < MLPH; mm++) {
            float acc = 0.0f;
            #pragma unroll
            for (int b = 0; b < NB; b++) acc += ef[b] * W[b * MLPH + mm];
            dst[p * MLPH + mm] = silu_f(acc);
        }
    }
}

// ---------------------------------------------------------------------------
// K2: node embedding h = node_attrs @ W_embed ; out[0..N) = node_attrs @ ae
// ---------------------------------------------------------------------------
__global__ __launch_bounds__(256) void k_embed(
    const float* __restrict__ na, const float* __restrict__ We,
    const float* __restrict__ ae, float* __restrict__ h, float* __restrict__ out)
{
    int i = blockIdx.x * 256 + threadIdx.x;   // [0, N*64)
    int n = i >> 6, c = i & 63;
    float acc = 0.0f, e0 = 0.0f;
    #pragma unroll
    for (int k = 0; k < NEL; k++) {
        float a = na[n * NEL + k];
        acc += a * We[k * C + c];
        e0 += a * ae[k];
    }
    h[i] = acc;
    if (c == 0) out[n] = e0;
}

// ---------------------------------------------------------------------------
// K3: h_up = h @ W_up[t]
// ---------------------------------------------------------------------------
__global__ __launch_bounds__(256) void k_up(
    const float* __restrict__ h, const float* __restrict__ Wup, float* __restrict__ hup)
{
    __shared__ float Wl[C * C];
    for (int i = threadIdx.x; i < C * C; i += 256) Wl[i] = Wup[i];
    __syncthreads();
    int o = threadIdx.x & 63, g = threadIdx.x >> 6;
    int n = blockIdx.x * 4 + g;
    const float* hr = h + n * C;
    float acc = 0.0f;
    #pragma unroll 8
    for (int c = 0; c < C; c++) acc += hr[c] * Wl[c * C + o];
    hup[n * C + o] = acc;
}

// ---------------------------------------------------------------------------
// K4 (hot): per-edge tensor-product message + atomic scatter into agg
// one wave processes 4 active edges per iteration; lane covers outputs
// j = lane + 64*jj (jj=0..8), i.e. (c,s) = (j/9, j%9)
// ---------------------------------------------------------------------------
__global__ __launch_bounds__(256) void k_msg(
    const int* __restrict__ cnt, const int* __restrict__ act_snd,
    const int* __restrict__ act_rcv, const float* __restrict__ act_sh,
    const float* __restrict__ act_h, const float* __restrict__ Wr2,
    const float* __restrict__ hup, float* __restrict__ agg)
{
    __shared__ float Wl[MLPH * CSH];   // 36 KB
    for (int i = threadIdx.x; i < MLPH * CSH; i += 256) Wl[i] = Wr2[i];
    __syncthreads();

    int lane = threadIdx.x & 63;
    int waveId = (blockIdx.x << 2) | (threadIdx.x >> 6);
    int nW = gridDim.x << 2;
    int nAct = *cnt;

    // per-lane (c,s) decomposition of j = lane + 64*jj
    int c9[9], s9[9];
    {
        int c = lane / 9, s = lane - c * 9;
        #pragma unroll
        for (int jj = 0; jj < 9; jj++) {
            c9[jj] = c; s9[jj] = s;
            c += 7; s += 1;
            if (s >= 9) { s -= 9; c += 1; }
        }
    }

    for (int k0 = waveId * 4; k0 < nAct; k0 += nW * 4) {
        float tw[4][9];
        #pragma unroll
        for (int e = 0; e < 4; e++)
            #pragma unroll
            for (int jj = 0; jj < 9; jj++) tw[e][jj] = 0.0f;

        int kk[4];
        bool val[4];
        float hidS[4];
        #pragma unroll
        for (int e = 0; e < 4; e++) {
            int k = k0 + e;
            val[e] = (k < nAct);
            kk[e] = val[e] ? k : k0;
            hidS[e] = (lane < MLPH) ? act_h[kk[e] * MLPH + lane] : 0.0f;
        }

        #pragma unroll
        for (int m = 0; m < MLPH; m++) {
            float hm0 = __shfl(hidS[0], m);
            float hm1 = __shfl(hidS[1], m);
            float hm2 = __shfl(hidS[2], m);
            float hm3 = __shfl(hidS[3], m);
            #pragma unroll
            for (int jj = 0; jj < 9; jj++) {
                float w = Wl[m * CSH + lane + (jj << 6)];
                tw[0][jj] += hm0 * w;
                tw[1][jj] += hm1 * w;
                tw[2][jj] += hm2 * w;
                tw[3][jj] += hm3 * w;
            }
        }

        #pragma unroll
        for (int e = 0; e < 4; e++) {
            if (!val[e]) continue;   // uniform across wave
            int k = kk[e];
            int snd = act_snd[k];
            int rcv = act_rcv[k];
            float hupS = hup[snd * C + lane];
            float shS = (lane < SHD) ? act_sh[k * SHD + lane] : 0.0f;
            float* ag = agg + rcv * CSH + lane;
            #pragma unroll
            for (int jj = 0; jj < 9; jj++) {
                float mult = __shfl(hupS, c9[jj]) * __shfl(shS, s9[jj]);
                atomicAdd(ag + (jj << 6), tw[e][jj] * mult);
            }
        }
    }
}

// ---------------------------------------------------------------------------
// K5: h_new = (agg/32) @ W_mix[t]  +  h @ W_self[t]
// block handles 16 nodes; agg tile staged in LDS
// ---------------------------------------------------------------------------
__global__ __launch_bounds__(256) void k_mix(
    const float* __restrict__ agg, const float* __restrict__ h,
    const float* __restrict__ Wmix, const float* __restrict__ Wself,
    float* __restrict__ hnew)
{
    __shared__ float Al[16 * CSH];   // 36 KB
    __shared__ float Hl[16 * C];     // 4 KB
    int nb = blockIdx.x * 16;
    for (int i = threadIdx.x; i < 16 * CSH; i += 256) Al[i] = agg[nb * CSH + i] * INV_AVG;
    for (int i = threadIdx.x; i < 16 * C; i += 256) Hl[i] = h[nb * C + i];
    __syncthreads();

    int o = threadIdx.x & 63, g = threadIdx.x >> 6;
    float acc[4] = {0.0f, 0.0f, 0.0f, 0.0f};
    for (int cs = 0; cs < CSH; cs++) {
        float w = Wmix[cs * C + o];
        #pragma unroll
        for (int q = 0; q < 4; q++) acc[q] += Al[(g + 4 * q) * CSH + cs] * w;
    }
    for (int c = 0; c < C; c++) {
        float w = Wself[c * C + o];
        #pragma unroll
        for (int q = 0; q < 4; q++) acc[q] += Hl[(g + 4 * q) * C + c] * w;
    }
    #pragma unroll
    for (int q = 0; q < 4; q++) hnew[(nb + g + 4 * q) * C + o] = acc[q];
}

// ---------------------------------------------------------------------------
// K6a: rep1[n] = h[n,:] . w_read
// ---------------------------------------------------------------------------
__global__ __launch_bounds__(256) void k_read(
    const float* __restrict__ h, const float* __restrict__ wread, float* __restrict__ out)
{
    int lane = threadIdx.x & 63;
    int n = blockIdx.x * 4 + (threadIdx.x >> 6);
    float v = h[n * C + lane] * wread[lane];
    #pragma unroll
    for (int off = 32; off; off >>= 1) v += __shfl_xor(v, off);
    if (lane == 0) out[n] = v;
}

// ---------------------------------------------------------------------------
// K6b: rep2[n] = silu(h[n,:] @ W_mlp1) . w_mlp2
// ---------------------------------------------------------------------------
__global__ __launch_bounds__(256) void k_read2(
    const float* __restrict__ h, const float* __restrict__ W1,
    const float* __restrict__ w2, float* __restrict__ out)
{
    int n = blockIdx.x * 256 + threadIdx.x;
    if (n >= N_NODES) return;
    float acc[MLPH];
    #pragma unroll
    for (int m = 0; m < MLPH; m++) acc[m] = 0.0f;
    for (int c = 0; c < C; c++) {
        float hv = h[n * C + c];
        #pragma unroll
        for (int m = 0; m < MLPH; m++) acc[m] += hv * W1[c * MLPH + m];
    }
    float o = 0.0f;
    #pragma unroll
    for (int m = 0; m < MLPH; m++) o += silu_f(acc[m]) * w2[m];
    out[n] = o;
}

// ---------------------------------------------------------------------------
extern "C" void kernel_launch(void* const* d_in, const int* in_sizes, int n_in,
                              void* d_out, int out_size, void* d_ws, size_t ws_size,
                              hipStream_t stream) {
    const float* pos    = (const float*)d_in[0];
    const float* na     = (const float*)d_in[1];
    const float* shifts = (const float*)d_in[2];
    const int*   ei     = (const int*)d_in[3];
    const float* ae     = (const float*)d_in[4];
    const float* We     = (const float*)d_in[5];
    const float* Wup    = (const float*)d_in[6];
    const float* Wr1    = (const float*)d_in[7];
    const float* Wr2    = (const float*)d_in[8];
    const float* Wmix   = (const float*)d_in[9];
    const float* Wself  = (const float*)d_in[10];
    const float* wread  = (const float*)d_in[11];
    const float* Wm1    = (const float*)d_in[12];
    const float* wm2    = (const float*)d_in[13];
    float* out = (float*)d_out;

    char* ws = (char*)d_ws;
    size_t off = 0;
    auto alloc = [&](size_t bytes) {
        off = (off + 255) & ~(size_t)255;
        void* p = ws + off;
        off += bytes;
        return p;
    };
    int*   cnt     = (int*)alloc(4);
    int*   act_snd = (int*)alloc((size_t)N_EDGES * 4);
    int*   act_rcv = (int*)alloc((size_t)N_EDGES * 4);
    float* act_sh  = (float*)alloc((size_t)N_EDGES * 9 * 4);
    float* act_h0  = (float*)alloc((size_t)N_EDGES * 16 * 4);
    float* act_h1  = (float*)alloc((size_t)N_EDGES * 16 * 4);
    float* hA      = (float*)alloc((size_t)N_NODES * C * 4);
    float* hB      = (float*)alloc((size_t)N_NODES * C * 4);
    float* hup     = (float*)alloc((size_t)N_NODES * C * 4);
    float* agg     = (float*)alloc((size_t)N_NODES * CSH * 4);

    hipMemsetAsync(cnt, 0, 4, stream);
    k_edge<<<N_EDGES / 256, 256, 0, stream>>>(pos, shifts, ei, Wr1, cnt,
                                              act_snd, act_rcv, act_sh, act_h0, act_h1);
    k_embed<<<(N_NODES * C) / 256, 256, 0, stream>>>(na, We, ae, hA, out);

    // ---- layer t = 0 ----
    k_up<<<N_NODES / 4, 256, 0, stream>>>(hA, Wup, hup);
    hipMemsetAsync(agg, 0, (size_t)N_NODES * CSH * 4, stream);
    k_msg<<<2048, 256, 0, stream>>>(cnt, act_snd, act_rcv, act_sh, act_h0,
                                    Wr2, hup, agg);
    k_mix<<<N_NODES / 16, 256, 0, stream>>>(agg, hA, Wmix, Wself, hB);
    k_read<<<N_NODES / 4, 256, 0, stream>>>(hB, wread, out + N_NODES);

    // ---- layer t = 1 ----
    k_up<<<N_NODES / 4, 256, 0, stream>>>(hB, Wup + C * C, hup);
    hipMemsetAsync(agg, 0, (size_t)N_NODES * CSH * 4, stream);
    k_msg<<<2048, 256, 0, stream>>>(cnt, act_snd, act_rcv, act_sh, act_h1,
                                    Wr2 + MLPH * CSH, hup, agg);
    k_mix<<<N_NODES / 16, 256, 0, stream>>>(agg, hB, Wmix + C * SHD * C,
                                            Wself + C * C, hA);
    k_read2<<<(N_NODES + 255) / 256, 256, 0, stream>>>(hA, Wm1, wm2, out + 2 * N_NODES);
}